// Round 6
// baseline (82.698 us; speedup 1.0000x reference)
//
#include <hip/hip_runtime.h>

#define NV    6890
#define NB    64
#define MAIN4 1722           // aligned float4 count per row ( (NV-2)/4 )
#define NITP  28             // scan iterations, padded to multiple of 4
#define ECAP  64             // CSR entries per row (fixed stride); overflow -> fallback
#define SCALE (1.0f / (64.0f * 6890.0f))

// ---------------------------------------------------------------------------
// Kernel 1: COMPRESS. One wave per row. Pure streaming: float4 ring-prefetch
// loads + ballot compaction + ~13 scattered 8B stores per row. No LDS, no
// gathers, nothing else consuming vmcnt -> row loads stay in flight.
// Entry order identical to R4's push order (deterministic).
// ---------------------------------------------------------------------------
__global__ __launch_bounds__(256) void compress_kernel(
    const float* __restrict__ L, float2* __restrict__ ent,
    int* __restrict__ cnt) {
  const int lane = threadIdx.x & 63;
  const int wv   = threadIdx.x >> 6;
  const int v    = blockIdx.x * 4 + wv;
  if (v >= NV) return;

  const float* __restrict__ row = L + (size_t)v * NV;
  const int head     = (v & 1) ? 2 : 0;          // odd rows: 8B-misaligned start
  const int extraPos = head ? 0 : (NV - 2);      // 2 floats outside the f4 body
  const float4* __restrict__ m4 = (const float4*)(row + head);
  const unsigned long long lmask = (1ull << lane) - 1ull;
  float2* __restrict__ re = ent + (size_t)v * ECAP;

  int nnz = 0;                                   // wave-uniform
  auto push = [&](bool nz, float val, int col) { // saturating CSR append
    unsigned long long m = __ballot(nz);
    int pos = nnz + __popcll(m & lmask);
    if (nz && pos < ECAP) re[pos] = make_float2(val, __int_as_float(col));
    nnz += __popcll(m);                          // keeps counting past ECAP
  };

  float4 buf[4];
  #pragma unroll
  for (int k = 0; k < 4; ++k) buf[k] = m4[k * 64 + lane];   // idx <= 255: valid

  {  // 2-float head (odd rows) / tail (even rows)
    const bool act = lane < 2;
    const float val = act ? row[extraPos + lane] : 0.f;
    push(act && val != 0.f, val, extraPos + lane);
  }

  #pragma unroll 4
  for (int it = 0; it < NITP; ++it) {
    const float4 f = buf[it & 3];
    const int i = it * 64 + lane;
    buf[it & 3] = m4[min((it + 4) * 64 + lane, MAIN4 - 1)]; // refill slot early
    const bool act = i < MAIN4;
    const int cb = head + i * 4;
    push(act && f.x != 0.f, f.x, cb);
    push(act && f.y != 0.f, f.y, cb + 1);
    push(act && f.z != 0.f, f.z, cb + 2);
    push(act && f.w != 0.f, f.w, cb + 3);
  }
  if (lane == 0) cnt[v] = nnz;
}

// ---------------------------------------------------------------------------
// Kernel 2: SPMM. One wave per row. Coalesced load of the row's entry list
// (lane j holds entry j), then uniform loop with readlane broadcast; lane
// owns output columns {lane, lane+64, lane+128}, gathered directly from x
// (no transposed copy needed -> transpose kernel eliminated).
// ---------------------------------------------------------------------------
template <bool USE_PARTIALS>
__global__ __launch_bounds__(256) void spmm_kernel(
    const float* __restrict__ L, const float* __restrict__ x,
    const float2* __restrict__ ent, const int* __restrict__ cnt,
    float* __restrict__ partials, float* __restrict__ out_atomic) {
  const int lane = threadIdx.x & 63;
  const int wv   = threadIdx.x >> 6;
  const int v    = blockIdx.x * 4 + wv;
  if (v >= NV) return;

  // Column ownership: lane handles columns {lane, lane+64, lane+128}.
  const int n0 = lane, n1 = lane + 64, n2 = lane + 128;
  const int o0 = (n0 / 3) * (NV * 3) + (n0 % 3);
  const int o1 = (n1 / 3) * (NV * 3) + (n1 % 3);
  const int o2 = (n2 / 3) * (NV * 3) + (n2 % 3);

  float a0 = 0.f, a1 = 0.f, a2 = 0.f;
  const int c = cnt[v];

  if (c <= ECAP) {
    const float2 e = (lane < c) ? ent[(size_t)v * ECAP + lane]
                                : make_float2(0.f, 0.f);
    #pragma unroll 2
    for (int j = 0; j < c; ++j) {
      const float val =
          __int_as_float(__builtin_amdgcn_readlane(__float_as_int(e.x), j));
      const int col = __builtin_amdgcn_readlane(__float_as_int(e.y), j);
      const int cb = col * 3;
      a0 = fmaf(val, x[cb + o0], a0);
      a1 = fmaf(val, x[cb + o1], a1);
      a2 = fmaf(val, x[cb + o2], a2);
    }
  } else {
    // Pathological row (>ECAP nonzeros; never for this input): dense re-scan.
    const float* __restrict__ row = L + (size_t)v * NV;
    const int head     = (v & 1) ? 2 : 0;
    const int extraPos = head ? 0 : (NV - 2);
    const float4* __restrict__ m4 = (const float4*)(row + head);
    auto walk = [&](unsigned long long m, float src, int col0, int stride) {
      while (m) {
        const int s = (int)__builtin_ctzll(m);
        m &= m - 1;
        const float val =
            __int_as_float(__builtin_amdgcn_readlane(__float_as_int(src), s));
        const int cb = (col0 + s * stride) * 3;
        a0 = fmaf(val, x[cb + o0], a0);
        a1 = fmaf(val, x[cb + o1], a1);
        a2 = fmaf(val, x[cb + o2], a2);
      }
    };
    {
      const bool act = lane < 2;
      const float val = act ? row[extraPos + lane] : 0.f;
      walk(__ballot(act && val != 0.f), val, extraPos, 1);
    }
    for (int it = 0; it < 27; ++it) {
      const int i = it * 64 + lane;
      const bool act = i < MAIN4;
      float4 f = make_float4(0.f, 0.f, 0.f, 0.f);
      if (act) f = m4[i];
      const int cb = head + it * 256;
      walk(__ballot(act && f.x != 0.f), f.x, cb + 0, 4);
      walk(__ballot(act && f.y != 0.f), f.y, cb + 1, 4);
      walk(__ballot(act && f.z != 0.f), f.z, cb + 2, 4);
      walk(__ballot(act && f.w != 0.f), f.w, cb + 3, 4);
    }
  }

  float sq = fmaf(a0, a0, fmaf(a1, a1, a2 * a2));
  #pragma unroll
  for (int o = 32; o > 0; o >>= 1) sq += __shfl_down(sq, o);
  if (lane == 0) {
    if (USE_PARTIALS) partials[v] = sq;
    else              atomicAdd(out_atomic, sq * SCALE);
  }
}

// ---------------------------------------------------------------------------
// Fallback fused kernel (small ws): R3-style bit-walk, gathers straight
// from x, no workspace needed beyond partials (or none, with atomics).
// ---------------------------------------------------------------------------
template <bool USE_PARTIALS>
__global__ __launch_bounds__(256) void lap_fused_kernel(
    const float* __restrict__ L, const float* __restrict__ x,
    float* __restrict__ partials, float* __restrict__ out_atomic) {
  const int lane = threadIdx.x & 63;
  const int wv   = threadIdx.x >> 6;
  const int v    = blockIdx.x * 4 + wv;
  if (v >= NV) return;

  const float* __restrict__ row = L + (size_t)v * NV;
  const int head     = (v & 1) ? 2 : 0;
  const int extraPos = head ? 0 : (NV - 2);
  const float4* __restrict__ m4 = (const float4*)(row + head);

  const int n0 = lane, n1 = lane + 64, n2 = lane + 128;
  const int o0 = (n0 / 3) * (NV * 3) + (n0 % 3);
  const int o1 = (n1 / 3) * (NV * 3) + (n1 % 3);
  const int o2 = (n2 / 3) * (NV * 3) + (n2 % 3);

  float a0 = 0.f, a1 = 0.f, a2 = 0.f;
  auto walk = [&](unsigned long long m, float src, int col0, int stride) {
    while (m) {
      const int s = (int)__builtin_ctzll(m);
      m &= m - 1;
      const float val =
          __int_as_float(__builtin_amdgcn_readlane(__float_as_int(src), s));
      const int cb = (col0 + s * stride) * 3;
      a0 = fmaf(val, x[cb + o0], a0);
      a1 = fmaf(val, x[cb + o1], a1);
      a2 = fmaf(val, x[cb + o2], a2);
    }
  };
  {
    const bool act = lane < 2;
    const float val = act ? row[extraPos + lane] : 0.f;
    walk(__ballot(act && val != 0.f), val, extraPos, 1);
  }
  for (int it = 0; it < 27; ++it) {
    const int i = it * 64 + lane;
    const bool act = i < MAIN4;
    float4 f = make_float4(0.f, 0.f, 0.f, 0.f);
    if (act) f = m4[i];
    const int cb = head + it * 256;
    walk(__ballot(act && f.x != 0.f), f.x, cb + 0, 4);
    walk(__ballot(act && f.y != 0.f), f.y, cb + 1, 4);
    walk(__ballot(act && f.z != 0.f), f.z, cb + 2, 4);
    walk(__ballot(act && f.w != 0.f), f.w, cb + 3, 4);
  }

  float sq = fmaf(a0, a0, fmaf(a1, a1, a2 * a2));
  #pragma unroll
  for (int o = 32; o > 0; o >>= 1) sq += __shfl_down(sq, o);
  if (lane == 0) {
    if (USE_PARTIALS) partials[v] = sq;
    else              atomicAdd(out_atomic, sq * SCALE);
  }
}

// ---------------------------------------------------------------------------
// Kernel 3: deterministic fixed-order reduction of the 6890 row partials.
// ---------------------------------------------------------------------------
__global__ __launch_bounds__(256) void reduce_kernel(
    const float* __restrict__ p, float* __restrict__ out) {
  int tid = threadIdx.x;
  float a = 0.0f;
  for (int i = tid; i < NV; i += 256) a += p[i];
  #pragma unroll
  for (int o = 32; o > 0; o >>= 1) a += __shfl_down(a, o);
  __shared__ float s_w[4];
  if ((tid & 63) == 0) s_w[tid >> 6] = a;
  __syncthreads();
  if (tid == 0) out[0] = (s_w[0] + s_w[1] + s_w[2] + s_w[3]) * SCALE;
}

__global__ void zero_out_kernel(float* p) {
  if (threadIdx.x == 0 && blockIdx.x == 0) p[0] = 0.0f;
}

// ---------------------------------------------------------------------------
extern "C" void kernel_launch(void* const* d_in, const int* in_sizes, int n_in,
                              void* d_out, int out_size, void* d_ws, size_t ws_size,
                              hipStream_t stream) {
  const float* x = (const float*)d_in[0];   // [64, 6890, 3] f32
  const float* L = (const float*)d_in[1];   // [6890, 6890] f32
  float* out = (float*)d_out;               // scalar f32

  const size_t ent_bytes  = (size_t)NV * ECAP * sizeof(float2);  // ~3.53 MB
  const size_t cnt_bytes  = (size_t)NV * sizeof(int);            // ~27.5 KB
  const size_t part_bytes = (size_t)NV * sizeof(float);          // ~27.5 KB
  const int grid = (NV + 3) / 4;

  if (ws_size >= ent_bytes + cnt_bytes + part_bytes) {
    float2* ent     = (float2*)d_ws;
    int*    cnt     = (int*)((char*)d_ws + ent_bytes);
    float*  partials = (float*)((char*)d_ws + ent_bytes + cnt_bytes);
    compress_kernel<<<grid, 256, 0, stream>>>(L, ent, cnt);
    spmm_kernel<true><<<grid, 256, 0, stream>>>(L, x, ent, cnt, partials, nullptr);
    reduce_kernel<<<1, 256, 0, stream>>>(partials, out);
  } else if (ws_size >= part_bytes) {
    float* partials = (float*)d_ws;
    lap_fused_kernel<true><<<grid, 256, 0, stream>>>(L, x, partials, nullptr);
    reduce_kernel<<<1, 256, 0, stream>>>(partials, out);
  } else {
    zero_out_kernel<<<1, 64, 0, stream>>>(out);
    lap_fused_kernel<false><<<grid, 256, 0, stream>>>(L, x, nullptr, out);
  }
}

// Round 7
// 60.945 us; speedup vs baseline: 1.3569x; 1.3569x over previous
//
#include <hip/hip_runtime.h>

#define NV    6890
#define NB    64
#define NCOL  192            // NB * 3 output columns per row
#define NC4   48             // NCOL/4 float4s per Xt row
#define MAIN4 1722           // aligned float4 count per row ( (NV-2)/4 )
#define NITP  32             // scan iterations padded to multiple of DEPTH
#define DEPTH 8              // prefetch ring depth (8 KB/wave in flight)
#define VCAP  128            // per-wave LDS nonzero-CHUNK capacity
#define SCALE (1.0f / (64.0f * 6890.0f))

// ---------------------------------------------------------------------------
// Kernel 1: transpose x[b][w][d] -> Xt[w][b*3+d]; writes coalesced, reads
// L2/L3-absorbed (x is 5.3 MB).
// ---------------------------------------------------------------------------
__global__ __launch_bounds__(256) void transpose_x_kernel(
    const float* __restrict__ x, float* __restrict__ Xt) {
  int i = blockIdx.x * blockDim.x + threadIdx.x;
  const int total = NV * NCOL;
  if (i >= total) return;
  int n = i % NCOL;
  int w = i / NCOL;
  Xt[i] = x[(size_t)(n / 3) * (NV * 3) + (size_t)w * 3 + (n % 3)];
}

// ---------------------------------------------------------------------------
// Kernel 2: ONE WAVE per row (2 waves / 128-thr block). Scan common path per
// float4: load + 3x v_or + ONE ballot + uniform rare-branch. Depth-8 ring,
// no LDS reads in loop, saturating chunk push (overflow checked after).
// Apply: uniform chunk loop; per nonzero component one 768B Xt-row gather
// (lanes 0..47, float4 each) + 4 FMAs. Deterministic order throughout.
// ---------------------------------------------------------------------------
template <bool USE_PARTIALS>
__global__ __launch_bounds__(128) void lap_rows_wave_kernel(
    const float* __restrict__ L,
    const float* __restrict__ Xt,
    float* __restrict__ partials,
    float* __restrict__ out_atomic) {
  const int lane = threadIdx.x & 63;
  const int wv   = threadIdx.x >> 6;
  const int v    = blockIdx.x * 2 + wv;
  if (v >= NV) return;                    // whole-wave exit; no barriers

  __shared__ float4 s_c4[2][VCAP];
  __shared__ int    s_cb[2][VCAP];
  float4* __restrict__ sc4 = s_c4[wv];
  int*    __restrict__ scb = s_cb[wv];

  const float* __restrict__ row = L + (size_t)v * NV;
  const int head     = (v & 1) ? 2 : 0;          // odd rows: 8B-misaligned start
  const int extraPos = head ? 0 : (NV - 2);      // 2 floats outside the f4 body
  const float4* __restrict__ m4 = (const float4*)(row + head);
  const unsigned long long lmask = (1ull << lane) - 1ull;

  int nnz = 0;                                   // wave-uniform chunk count

  auto pushc = [&](unsigned long long m, float4 f, int colbase) {
    if (m) {                                     // wave-uniform rare branch
      const int pos = nnz + __popcll(m & lmask);
      const bool mine = (m >> lane) & 1ull;
      if (mine && pos < VCAP) { sc4[pos] = f; scb[pos] = colbase; }
      nnz += __popcll(m);                        // saturating: count past VCAP
    }
  };

  // ---- Phase 1: scan -------------------------------------------------------
  { // 2-float head (odd) / tail (even): all lanes broadcast-load, lane 0 owns.
    const float h0 = row[extraPos];
    const float h1 = row[extraPos + 1];
    const bool nz = (lane == 0) &&
                    ((__float_as_uint(h0) | __float_as_uint(h1)) != 0u);
    pushc(__ballot(nz), make_float4(h0, h1, 0.f, 0.f), extraPos);
  }

  float4 buf[DEPTH];
  #pragma unroll
  for (int k = 0; k < DEPTH; ++k) buf[k] = m4[k * 64 + lane];  // max 511 < MAIN4

  #pragma unroll DEPTH
  for (int it = 0; it < NITP; ++it) {
    const float4 f = buf[it & (DEPTH - 1)];
    buf[it & (DEPTH - 1)] = m4[min((it + DEPTH) * 64 + lane, MAIN4 - 1)];
    const int i = it * 64 + lane;
    const unsigned u = __float_as_uint(f.x) | __float_as_uint(f.y) |
                       __float_as_uint(f.z) | __float_as_uint(f.w);
    pushc(__ballot((i < MAIN4) && (u != 0u)), f, head + i * 4);
  }

  // ---- Phase 2: apply ------------------------------------------------------
  float4 acc = make_float4(0.f, 0.f, 0.f, 0.f);

  auto gatherc = [&](float val, int col) {       // one column's 768B Xt row
    if (lane < NC4) {
      const float4 g = ((const float4*)Xt)[(size_t)col * NC4 + lane];
      acc.x = fmaf(val, g.x, acc.x);
      acc.y = fmaf(val, g.y, acc.y);
      acc.z = fmaf(val, g.z, acc.z);
      acc.w = fmaf(val, g.w, acc.w);
    }
  };

  if (nnz <= VCAP) {
    const int cnt = nnz;
    for (int j = 0; j < cnt; ++j) {              // uniform j: LDS broadcast
      const float4 c = sc4[j];
      const int   cb = scb[j];
      if (__float_as_uint(c.x)) gatherc(c.x, cb);
      if (__float_as_uint(c.y)) gatherc(c.y, cb + 1);
      if (__float_as_uint(c.z)) gatherc(c.z, cb + 2);
      if (__float_as_uint(c.w)) gatherc(c.w, cb + 3);
    }
  } else {
    // Pathological row (>VCAP nonzero chunks; never for this input):
    // deterministic dense re-walk, value-granular, gathers from Xt.
    acc = make_float4(0.f, 0.f, 0.f, 0.f);
    auto walk = [&](unsigned long long m, float src, int col0, int stride) {
      while (m) {
        const int s = (int)__builtin_ctzll(m);
        m &= m - 1;
        const float val =
            __int_as_float(__builtin_amdgcn_readlane(__float_as_int(src), s));
        gatherc(val, col0 + s * stride);
      }
    };
    {
      const bool act = lane < 2;
      const float val = act ? row[extraPos + lane] : 0.f;
      walk(__ballot(act && val != 0.f), val, extraPos, 1);
    }
    for (int it = 0; it < 27; ++it) {
      const int i = it * 64 + lane;
      const bool act = i < MAIN4;
      float4 f = make_float4(0.f, 0.f, 0.f, 0.f);
      if (act) f = m4[i];
      const int cb = head + it * 256;
      walk(__ballot(act && f.x != 0.f), f.x, cb + 0, 4);
      walk(__ballot(act && f.y != 0.f), f.y, cb + 1, 4);
      walk(__ballot(act && f.z != 0.f), f.z, cb + 2, 4);
      walk(__ballot(act && f.w != 0.f), f.w, cb + 3, 4);
    }
  }

  // ---- Row contribution ----------------------------------------------------
  float sq = fmaf(acc.x, acc.x,
             fmaf(acc.y, acc.y,
             fmaf(acc.z, acc.z, acc.w * acc.w)));
  #pragma unroll
  for (int o = 32; o > 0; o >>= 1) sq += __shfl_down(sq, o);
  if (lane == 0) {
    if (USE_PARTIALS) partials[v] = sq;
    else              atomicAdd(out_atomic, sq * SCALE);
  }
}

// ---------------------------------------------------------------------------
// Fallback fused kernel (tiny ws): R3-style bit-walk, gathers from x.
// ---------------------------------------------------------------------------
template <bool USE_PARTIALS>
__global__ __launch_bounds__(256) void lap_fused_kernel(
    const float* __restrict__ L, const float* __restrict__ x,
    float* __restrict__ partials, float* __restrict__ out_atomic) {
  const int lane = threadIdx.x & 63;
  const int wv   = threadIdx.x >> 6;
  const int v    = blockIdx.x * 4 + wv;
  if (v >= NV) return;

  const float* __restrict__ row = L + (size_t)v * NV;
  const int head     = (v & 1) ? 2 : 0;
  const int extraPos = head ? 0 : (NV - 2);
  const float4* __restrict__ m4 = (const float4*)(row + head);

  const int n0 = lane, n1 = lane + 64, n2 = lane + 128;
  const int o0 = (n0 / 3) * (NV * 3) + (n0 % 3);
  const int o1 = (n1 / 3) * (NV * 3) + (n1 % 3);
  const int o2 = (n2 / 3) * (NV * 3) + (n2 % 3);

  float a0 = 0.f, a1 = 0.f, a2 = 0.f;
  auto walk = [&](unsigned long long m, float src, int col0, int stride) {
    while (m) {
      const int s = (int)__builtin_ctzll(m);
      m &= m - 1;
      const float val =
          __int_as_float(__builtin_amdgcn_readlane(__float_as_int(src), s));
      const int cb = (col0 + s * stride) * 3;
      a0 = fmaf(val, x[cb + o0], a0);
      a1 = fmaf(val, x[cb + o1], a1);
      a2 = fmaf(val, x[cb + o2], a2);
    }
  };
  {
    const bool act = lane < 2;
    const float val = act ? row[extraPos + lane] : 0.f;
    walk(__ballot(act && val != 0.f), val, extraPos, 1);
  }
  for (int it = 0; it < 27; ++it) {
    const int i = it * 64 + lane;
    const bool act = i < MAIN4;
    float4 f = make_float4(0.f, 0.f, 0.f, 0.f);
    if (act) f = m4[i];
    const int cb = head + it * 256;
    walk(__ballot(act && f.x != 0.f), f.x, cb + 0, 4);
    walk(__ballot(act && f.y != 0.f), f.y, cb + 1, 4);
    walk(__ballot(act && f.z != 0.f), f.z, cb + 2, 4);
    walk(__ballot(act && f.w != 0.f), f.w, cb + 3, 4);
  }

  float sq = fmaf(a0, a0, fmaf(a1, a1, a2 * a2));
  #pragma unroll
  for (int o = 32; o > 0; o >>= 1) sq += __shfl_down(sq, o);
  if (lane == 0) {
    if (USE_PARTIALS) partials[v] = sq;
    else              atomicAdd(out_atomic, sq * SCALE);
  }
}

// ---------------------------------------------------------------------------
// Kernel 3: deterministic fixed-order reduction of the 6890 row partials.
// ---------------------------------------------------------------------------
__global__ __launch_bounds__(256) void reduce_kernel(
    const float* __restrict__ p, float* __restrict__ out) {
  int tid = threadIdx.x;
  float a = 0.0f;
  for (int i = tid; i < NV; i += 256) a += p[i];
  #pragma unroll
  for (int o = 32; o > 0; o >>= 1) a += __shfl_down(a, o);
  __shared__ float s_w[4];
  if ((tid & 63) == 0) s_w[tid >> 6] = a;
  __syncthreads();
  if (tid == 0) out[0] = (s_w[0] + s_w[1] + s_w[2] + s_w[3]) * SCALE;
}

__global__ void zero_out_kernel(float* p) {
  if (threadIdx.x == 0 && blockIdx.x == 0) p[0] = 0.0f;
}

// ---------------------------------------------------------------------------
extern "C" void kernel_launch(void* const* d_in, const int* in_sizes, int n_in,
                              void* d_out, int out_size, void* d_ws, size_t ws_size,
                              hipStream_t stream) {
  const float* x = (const float*)d_in[0];   // [64, 6890, 3] f32
  const float* L = (const float*)d_in[1];   // [6890, 6890] f32
  float* out = (float*)d_out;               // scalar f32

  const size_t xt_bytes   = (size_t)NV * NCOL * sizeof(float);  // ~5.3 MB
  const size_t part_bytes = (size_t)NV * sizeof(float);         // ~27.5 KB

  if (ws_size >= xt_bytes + part_bytes) {
    float* Xt       = (float*)d_ws;
    float* partials = (float*)((char*)d_ws + xt_bytes);
    const int total = NV * NCOL;
    transpose_x_kernel<<<(total + 255) / 256, 256, 0, stream>>>(x, Xt);
    lap_rows_wave_kernel<true><<<(NV + 1) / 2, 128, 0, stream>>>(L, Xt, partials, nullptr);
    reduce_kernel<<<1, 256, 0, stream>>>(partials, out);
  } else if (ws_size >= part_bytes) {
    float* partials = (float*)d_ws;
    lap_fused_kernel<true><<<(NV + 3) / 4, 256, 0, stream>>>(L, x, partials, nullptr);
    reduce_kernel<<<1, 256, 0, stream>>>(partials, out);
  } else {
    zero_out_kernel<<<1, 64, 0, stream>>>(out);
    lap_fused_kernel<false><<<(NV + 3) / 4, 256, 0, stream>>>(L, x, nullptr, out);
  }
}